// Round 6
// baseline (543.015 us; speedup 1.0000x reference)
//
#include <hip/hip_runtime.h>
#include <hip/hip_cooperative_groups.h>

namespace cg = cooperative_groups;

#define DMODEL 1024
#define DSTATE 16
#define DCONV  4
#define DINNER 2048
#define BSZ    2
#define LSEQ   2048
#define MTOT   (BSZ * LSEQ)   // 4096 rows for all GEMMs
#define NCH    64             // scan chunks per sequence
#define LC     (LSEQ / NCH)   // 32 timesteps per chunk
#define LOG2E  1.44269504088896f

typedef unsigned short u16;
typedef __attribute__((ext_vector_type(8))) short short8;           // 8 bf16 (MFMA A/B frag)
typedef __attribute__((ext_vector_type(8))) unsigned short u16x8;   // 16B bf16 chunk
typedef __attribute__((ext_vector_type(4))) float f32x4;            // MFMA C/D frag

__device__ __forceinline__ float silu_f(float v) {
  return v * __builtin_amdgcn_rcpf(1.f + __builtin_amdgcn_exp2f(-v * LOG2E));
}

__device__ __forceinline__ u16 f2bf(float f) {   // RNE f32 -> bf16
  unsigned int u = __float_as_uint(f);
  u += 0x7FFF + ((u >> 16) & 1);
  return (u16)(u >> 16);
}
__device__ __forceinline__ float bf2f(u16 b) { return __uint_as_float(((unsigned int)b) << 16); }

// async global->LDS, 16B/lane; LDS dest = wave-uniform base + lane*16 (m104)
__device__ __forceinline__ void gload_lds16(const u16* g, u16* l) {
  __builtin_amdgcn_global_load_lds((const __attribute__((address_space(1))) unsigned int*)g,
                                   (__attribute__((address_space(3))) unsigned int*)l, 16, 0, 0);
}

// All four f32->bf16 casts in one dispatch (x, W_in, W_dt, W_out), row-major
__global__ __launch_bounds__(256)
void cast4(const float4* __restrict__ s0, ushort4* __restrict__ d0, int n0,
           const float4* __restrict__ s1, ushort4* __restrict__ d1, int n1,
           const float4* __restrict__ s2, ushort4* __restrict__ d2, int n2,
           const float4* __restrict__ s3, ushort4* __restrict__ d3, int n3) {
  int i = blockIdx.x * 256 + threadIdx.x;
  const float4* s; ushort4* d;
  if (i < n0)                { s = s0; d = d0; }
  else if ((i -= n0) < n1)   { s = s1; d = d1; }
  else if ((i -= n1) < n2)   { s = s2; d = d2; }
  else if ((i -= n2) < n3)   { s = s3; d = d3; }
  else return;
  float4 v = s[i];
  ushort4 o = { f2bf(v.x), f2bf(v.y), f2bf(v.z), f2bf(v.w) };
  d[i] = o;
}

// ---- single-barrier phased 256xBN GEMM (round-3 best-measured form) --------
// BK=64 per K-tile, 2 K-tiles per iteration, 8 waves (4M x 2N), per-wave
// output 64 x BN/2; 16 MFMA per phase. LDS double-buffer A[2][256][64] +
// B[2][BN][64] (128 KB / 96 KB, dynamic). fm/gsz 4-M-group block swizzle.
// Phase = { ds_reads; STG; MFMA x16; lgkmcnt(0); [vmcnt(4) at K-tile end];
//           s_barrier }. Direct scalar C stores (measured best, r3 vs r4).
template<int BN, int MODE, int OBF>
__global__ __launch_bounds__(512, 2)
void gemm8p(const u16* __restrict__ A, const u16* __restrict__ Bm,
            const float* __restrict__ bias, void* __restrict__ Cv,
            int M, int N, int K) {
  constexpr int BT  = BN / 32;    // B frags per wave (8 or 4)
  constexpr int TJP = 2;          // tj per phase -> 16 MFMA per phase
  constexpr int NPH = BT / TJP;   // phases per K-tile (4 or 2)
  constexpr int NBH = BN / 128;   // B half-tiles per K-tile (2 or 1)
  extern __shared__ __align__(16) u16 smem[];
  u16* As = smem;                     // [2][256][64]
  u16* Bs = smem + 2 * 256 * 64;      // [2][BN][64]

  const int tid  = threadIdx.x;
  const int lane = tid & 63;
  const int w    = tid >> 6;
  const int quad = lane >> 4;
  const int l16  = lane & 15;
  const int wm   = (w >> 1) * 64;         // 4 M-warps
  const int wn   = (w & 1) * (BN / 2);    // 2 N-warps

  const int nbn = N / BN, nbm = M >> 8;
  const int pid = blockIdx.x;
  const int npg = 4 * nbn;
  const int fm  = (pid / npg) * 4;
  const int gsz = (nbm - fm < 4) ? (nbm - fm) : 4;
  const int bm  = (fm + (pid % gsz)) << 8;
  const int bn  = ((pid % npg) / gsz) * BN;

  const int rseg = lane >> 3;
  const int cd8  = (((lane & 7) ^ rseg) << 3);
  const u16* gA = A  + (size_t)(bm + 16 * w + rseg) * K + cd8;
  const u16* gB = Bm + (size_t)(bn + 16 * w + rseg) * K + cd8;
  u16* lA = &As[(2 * w) << 9];
  u16* lB = &Bs[(2 * w) << 9];
  const int Kmask = K - 1;

  auto stA = [&](int slot, int h, int kt) {   // stage A half-tile h of K-tile kt
    const size_t go = (size_t)h * 128 * K + ((kt << 6) & Kmask);
    gload_lds16(gA + go,         lA + slot * 16384 + h * 8192);
    gload_lds16(gA + go + 8 * K, lA + slot * 16384 + h * 8192 + 512);
  };
  auto stB = [&](int slot, int h, int kt) {
    const size_t go = (size_t)h * 128 * K + ((kt << 6) & Kmask);
    gload_lds16(gB + go,         lB + slot * (BN * 64) + h * 8192);
    gload_lds16(gB + go + 8 * K, lB + slot * (BN * 64) + h * 8192 + 512);
  };

  int aoff[4][2], boff[BT][2];
#pragma unroll
  for (int t = 0; t < 4; ++t) {
    const int ra = wm + 16 * t + l16;
#pragma unroll
    for (int ks = 0; ks < 2; ++ks)
      aoff[t][ks] = ra * 64 + (((quad + 4 * ks) ^ (ra & 7)) << 3);
  }
#pragma unroll
  for (int tj = 0; tj < BT; ++tj) {
    const int rb = wn + 16 * tj + l16;
#pragma unroll
    for (int ks = 0; ks < 2; ++ks)
      boff[tj][ks] = rb * 64 + (((quad + 4 * ks) ^ (rb & 7)) << 3);
  }

  f32x4 acc[4][BT] = {};
  short8 af[4][2];

#define RD_AF(slot)                                                          \
  { _Pragma("unroll") for (int t = 0; t < 4; ++t)                            \
      _Pragma("unroll") for (int ks = 0; ks < 2; ++ks)                       \
        af[t][ks] = *(const short8*)&As[(slot) * 16384 + aoff[t][ks]]; }

#define VM4 asm volatile("s_waitcnt vmcnt(4)" ::: "memory")
#define NOWAIT ((void)0)

#define PHASE(slot, j, STG, WAIT)                                            \
  {                                                                          \
    if ((j) == 0) RD_AF(slot);                                               \
    short8 bfp[TJP][2];                                                      \
    _Pragma("unroll") for (int jj = 0; jj < TJP; ++jj)                       \
      _Pragma("unroll") for (int ks = 0; ks < 2; ++ks)                       \
        bfp[jj][ks] = *(const short8*)&Bs[(slot) * (BN * 64) +               \
                                          boff[(j) * TJP + jj][ks]];         \
    STG;                                                                     \
    __builtin_amdgcn_s_setprio(1);                                           \
    _Pragma("unroll") for (int ks = 0; ks < 2; ++ks)                         \
      _Pragma("unroll") for (int jj = 0; jj < TJP; ++jj)                     \
        _Pragma("unroll") for (int t = 0; t < 4; ++t)                        \
          acc[t][(j) * TJP + jj] = __builtin_amdgcn_mfma_f32_16x16x32_bf16(  \
              af[t][ks], bfp[jj][ks], acc[t][(j) * TJP + jj], 0, 0, 0);      \
    __builtin_amdgcn_s_setprio(0);                                           \
    asm volatile("s_waitcnt lgkmcnt(0)" ::: "memory");                       \
    WAIT;                                                                    \
    __builtin_amdgcn_s_barrier();                                            \
  }

  stA(0, 0, 0); stA(0, 1, 0);
  stB(0, 0, 0); if (NBH == 2) stB(0, 1, 0);
  stA(1, 0, 1); stA(1, 1, 1);
  VM4;
  __builtin_amdgcn_s_barrier();

  const int niter = K >> 7;
  for (int i = 0; i < niter; ++i) {
    const int tb1 = 2 * i + 1, t2 = 2 * i + 2, t3 = 2 * i + 3;
    if constexpr (NPH == 4) {
      PHASE(0, 0, { stB(1, 0, tb1); },               NOWAIT);
      PHASE(0, 1, { stB(1, 1, tb1); stA(0, 0, t2); }, NOWAIT);
      PHASE(0, 2, { stA(0, 1, t2); },                NOWAIT);
      PHASE(0, 3, {},                                VM4);
      PHASE(1, 0, { stB(0, 0, t2); },                NOWAIT);
      PHASE(1, 1, { stB(0, 1, t2); stA(1, 0, t3); }, NOWAIT);
      PHASE(1, 2, { stA(1, 1, t3); },                NOWAIT);
      PHASE(1, 3, {},                                VM4);
    } else {
      PHASE(0, 0, { stB(1, 0, tb1); },                NOWAIT);
      PHASE(0, 1, { stA(0, 0, t2); stA(0, 1, t2); },  VM4);
      PHASE(1, 0, { stB(0, 0, t2); },                 NOWAIT);
      PHASE(1, 1, { stA(1, 0, t3); stA(1, 1, t3); },  VM4);
    }
  }
#undef PHASE
#undef RD_AF
#undef VM4
#undef NOWAIT

  asm volatile("s_waitcnt vmcnt(0)" ::: "memory");   // drain wrapped prefetches

  // C/D: col = lane&15, row = quad*4 + reg (m89/m91)
#pragma unroll
  for (int t = 0; t < 4; ++t) {
    const int row0 = bm + wm + 16 * t + quad * 4;
#pragma unroll
    for (int tj = 0; tj < BT; ++tj) {
      const int col = bn + wn + 16 * tj + l16;
      const float bv = (MODE == 1) ? bias[col] : 0.f;
#pragma unroll
      for (int i2 = 0; i2 < 4; ++i2) {
        float v = acc[t][tj][i2] + bv;
        if (MODE == 1) v = (v > 20.f) ? v : __logf(1.f + __expf(v));   // softplus
        if (OBF) ((u16*)Cv)[(size_t)(row0 + i2) * N + col] = f2bf(v);
        else     ((float*)Cv)[(size_t)(row0 + i2) * N + col] = v;
      }
    }
  }
}

// ---- 128xBN-tile GEMM, BK=128 (GEMM3 BN=64; round-0 measured form) ---------
template<int MODE, int OBF, int BN>
__global__ __launch_bounds__(256)
void hgemm_bk128(const u16* __restrict__ A, const u16* __restrict__ B,
                 const float* __restrict__ bias, void* __restrict__ Cv,
                 int M, int N, int K) {
  constexpr int ASEG = 32;            // A: 128 rows x 256 B = 32 KB
  constexpr int BSEG = BN / 4;        // B: BN rows x 256 B
  constexpr int SPW  = (ASEG + BSEG) / 4;
  constexpr int BT   = BN / 32;       // B frags per wave (4 or 2)
  __shared__ u16 As[128 * 128];       // 32 KB
  __shared__ u16 Bs[BN * 128];        // 32 or 16 KB
  const int tid  = threadIdx.x;
  const int lane = tid & 63;
  const int w    = tid >> 6;
  const int quad = lane >> 4;
  const int l16  = lane & 15;

  const int nbn = N / BN, nbm = M >> 7;
  const int pid = blockIdx.x;
  const int npg = 4 * nbn;
  const int fm  = (pid / npg) * 4;
  const int gsz = (nbm - fm < 4) ? (nbm - fm) : 4;
  const int bm  = (fm + (pid % gsz)) << 7;
  const int bn  = ((pid % npg) / gsz) * BN;

  const int wm = (w & 1) * 64;
  const int wn = (w >> 1) * (BN / 2);

  const int rs4 = lane >> 4;
  const u16* Gp[SPW]; u16* Lp[SPW];
#pragma unroll
  for (int q = 0; q < SPW; ++q) {
    const int g = w * SPW + q;
    if (g < ASEG) {
      const int r  = g * 4 + rs4;
      const int cdk = (lane & 15) ^ (r & 15);
      Gp[q] = A + (size_t)(bm + r) * K + (cdk << 3);
      Lp[q] = &As[g << 9];
    } else {
      const int r  = (g - ASEG) * 4 + rs4;
      const int cdk = (lane & 15) ^ (r & 15);
      Gp[q] = B + (size_t)(bn + r) * K + (cdk << 3);
      Lp[q] = &Bs[(g - ASEG) << 9];
    }
  }

  const short8* Afp[4][4];
  const short8* Bfp[BT][4];
#pragma unroll
  for (int t = 0; t < 4; ++t) {
    const int ra = wm + 16 * t + l16;
#pragma unroll
    for (int ks = 0; ks < 4; ++ks)
      Afp[t][ks] = (const short8*)&As[ra * 128 + (((quad + 4 * ks) ^ (ra & 15)) << 3)];
  }
#pragma unroll
  for (int t = 0; t < BT; ++t) {
    const int rb = wn + 16 * t + l16;
#pragma unroll
    for (int ks = 0; ks < 4; ++ks)
      Bfp[t][ks] = (const short8*)&Bs[rb * 128 + (((quad + 4 * ks) ^ (rb & 15)) << 3)];
  }

  f32x4 acc[4][BT] = {};

  for (int k0 = 0; k0 < K; k0 += 128) {
#pragma unroll
    for (int q = 0; q < SPW; ++q) { gload_lds16(Gp[q], Lp[q]); Gp[q] += 128; }
    __syncthreads();
#pragma unroll
    for (int ks = 0; ks < 4; ++ks) {
      short8 af[4], bf[BT];
#pragma unroll
      for (int t = 0; t < 4; ++t) af[t] = *Afp[t][ks];
#pragma unroll
      for (int t = 0; t < BT; ++t) bf[t] = *Bfp[t][ks];
#pragma unroll
      for (int ti = 0; ti < 4; ++ti)
#pragma unroll
        for (int tj = 0; tj < BT; ++tj)
          acc[ti][tj] = __builtin_amdgcn_mfma_f32_16x16x32_bf16(af[ti], bf[tj],
                                                                acc[ti][tj], 0, 0, 0);
    }
    __syncthreads();
  }

#pragma unroll
  for (int ti = 0; ti < 4; ++ti) {
    const int row0 = bm + wm + 16 * ti + quad * 4;
#pragma unroll
    for (int tj = 0; tj < BT; ++tj) {
      const int col = bn + wn + 16 * tj + l16;
      const float bv = (MODE == 1) ? bias[col] : 0.f;
#pragma unroll
      for (int i = 0; i < 4; ++i) {
        float v = acc[ti][tj][i] + bv;
        if (MODE == 1) v = (v > 20.f) ? v : __logf(1.f + __expf(v));
        if (OBF) ((u16*)Cv)[(size_t)(row0 + i) * N + col] = f2bf(v);
        else     ((float*)Cv)[(size_t)(row0 + i) * N + col] = v;
      }
    }
  }
}

// depthwise causal conv1d (taps=4) + bias + SiLU; thread per (t, 8-channel octet)
__global__ __launch_bounds__(256)
void conv_silu(const u16* __restrict__ xz, const float* __restrict__ conv_w,
               const float* __restrict__ conv_b, u16* __restrict__ xact) {
  const int i = blockIdx.x * 256 + threadIdx.x;  // MTOT * 256 octets = 2^20
  const int ko = i & 255;
  const int t  = (i >> 8) & (LSEQ - 1);
  const int b  = i >> 19;
  const int c  = ko << 3;
  float a[8];
  float4 w[8];
#pragma unroll
  for (int j = 0; j < 8; ++j) {
    a[j] = conv_b[c + j];
    w[j] = *(const float4*)(conv_w + (c + j) * DCONV);
  }
#pragma unroll
  for (int k = 0; k < DCONV; ++k) {
    const int tt = t + k - (DCONV - 1);
    if (tt >= 0) {
      const u16x8 v = *(const u16x8*)(xz + ((size_t)(b * LSEQ + tt) << 12) + c);
#pragma unroll
      for (int j = 0; j < 8; ++j)
        a[j] = fmaf(bf2f(v[j]), ((const float*)&w[j])[k], a[j]);
    }
  }
  u16x8 o;
#pragma unroll
  for (int j = 0; j < 8; ++j) o[j] = f2bf(silu_f(a[j]));
  *(u16x8*)(xact + ((size_t)(b * LSEQ + t) << 11) + c) = o;
}

// ---- chunked parallel scan -------------------------------------------------
// Fused cooperative form (one dispatch, 2 grid.sync) with guarded fallback to
// the 3-kernel form. Grid 1024 x 256 = 4 blocks/CU co-resident;
// __launch_bounds__(256,4) caps VGPR at 128 so residency holds.

__device__ __forceinline__ void scan_p1_core(
    int c, int ch, int b, const float* a2, const u16* __restrict__ dtb,
    const u16* __restrict__ xact, u16* __restrict__ hbuf,
    float* __restrict__ sumdt) {
  const size_t base = ((size_t)(b * LSEQ + ch * LC) << 11) + c;
  float h[16] = {};
  float sd = 0.f;
  for (int j = 0; j < LC; j += 2) {
    const float dt0 = bf2f(dtb [base + ((size_t)j << 11)]);
    const float xv0 = bf2f(xact[base + ((size_t)j << 11)]);
    const float dt1 = bf2f(dtb [base + ((size_t)(j + 1) << 11)]);
    const float xv1 = bf2f(xact[base + ((size_t)(j + 1) << 11)]);
    const float dx0 = dt0 * xv0, dx1 = dt1 * xv1;
    sd += dt0 + dt1;
#pragma unroll
    for (int s = 0; s < 16; ++s)
      h[s] = fmaf(__builtin_amdgcn_exp2f(dt0 * a2[s]), h[s], dx0);
#pragma unroll
    for (int s = 0; s < 16; ++s)
      h[s] = fmaf(__builtin_amdgcn_exp2f(dt1 * a2[s]), h[s], dx1);
  }
  u16x8* ho = (u16x8*)&hbuf[(((size_t)(b * NCH + ch) * DINNER) + c) << 4];
  u16x8 lo, hi;
#pragma unroll
  for (int s = 0; s < 8; ++s) { lo[s] = f2bf(h[s]); hi[s] = f2bf(h[8 + s]); }
  ho[0] = lo; ho[1] = hi;
  sumdt[(size_t)(b * NCH + ch) * DINNER + c] = sd;
}

__device__ __forceinline__ void scan_comb_core(
    int gid, u16* __restrict__ hbuf, const float* __restrict__ sumdt,
    const float* __restrict__ A_log) {
  const int s = gid & 15;
  const int c = (gid >> 4) & (DINNER - 1);
  const int b = gid >> 15;
  const float a2 = -__expf(A_log[c * DSTATE + s]) * LOG2E;
  float h = 0.f;
  for (int k = 0; k < NCH; ++k) {
    const size_t o = (((size_t)(b * NCH + k) * DINNER) + c) * 16 + s;
    const float he = bf2f(hbuf[o]);
    const float sd = sumdt[(size_t)(b * NCH + k) * DINNER + c];
    hbuf[o] = f2bf(h);                    // h_start for chunk k
    h = fmaf(__builtin_amdgcn_exp2f(sd * a2), h, he);
  }
}

__device__ __forceinline__ void scan_p3_core(
    int c, int ch, int b, const float* a2, float dp,
    const u16* __restrict__ dtb, const u16* __restrict__ xact,
    const u16* __restrict__ xz, const u16* __restrict__ hbuf,
    u16* __restrict__ yg) {
  float h[16];
  const u16x8* hi = (const u16x8*)&hbuf[(((size_t)(b * NCH + ch) * DINNER) + c) << 4];
  const u16x8 vlo = hi[0], vhi = hi[1];
#pragma unroll
  for (int s = 0; s < 8; ++s) { h[s] = bf2f(vlo[s]); h[8 + s] = bf2f(vhi[s]); }
  const size_t base  = ((size_t)(b * LSEQ + ch * LC) << 11) + c;
  const size_t zbase = ((size_t)(b * LSEQ + ch * LC) << 12) + DINNER + c;
  for (int j = 0; j < LC; j += 2) {
    const float dt0 = bf2f(dtb [base + ((size_t)j << 11)]);
    const float xv0 = bf2f(xact[base + ((size_t)j << 11)]);
    const float zv0 = bf2f(xz[zbase + ((size_t)j << 12)]);
    const float dt1 = bf2f(dtb [base + ((size_t)(j + 1) << 11)]);
    const float xv1 = bf2f(xact[base + ((size_t)(j + 1) << 11)]);
    const float zv1 = bf2f(xz[zbase + ((size_t)(j + 1) << 12)]);
    const float dx0 = dt0 * xv0, dx1 = dt1 * xv1;
    float y0 = 0.f, y1 = 0.f;
#pragma unroll
    for (int s = 0; s < 16; ++s) {
      h[s] = fmaf(__builtin_amdgcn_exp2f(dt0 * a2[s]), h[s], dx0);
      y0 += h[s];
    }
#pragma unroll
    for (int s = 0; s < 16; ++s) {
      h[s] = fmaf(__builtin_amdgcn_exp2f(dt1 * a2[s]), h[s], dx1);
      y1 += h[s];
    }
    y0 = fmaf(dp, xv0, y0);
    y1 = fmaf(dp, xv1, y1);
    yg[base + ((size_t)j << 11)]       = f2bf(y0 * silu_f(zv0));
    yg[base + ((size_t)(j + 1) << 11)] = f2bf(y1 * silu_f(zv1));
  }
}

__global__ __launch_bounds__(256, 4)
void scan_fused(const u16* __restrict__ dtb, const u16* __restrict__ xact,
                const u16* __restrict__ xz, const float* __restrict__ A_log,
                const float* __restrict__ Dp, u16* __restrict__ hbuf,
                float* __restrict__ sumdt, u16* __restrict__ yg) {
  cg::grid_group grid = cg::this_grid();
  const int gid = blockIdx.x * 256 + threadIdx.x;
  const int c  = gid & (DINNER - 1);
  const int ch = (gid >> 11) & (NCH - 1);
  const int b  = gid >> 17;
  float a2[16];
#pragma unroll
  for (int s = 0; s < 16; ++s)
    a2[s] = -__expf(A_log[c * DSTATE + s]) * LOG2E;
  const float dp = Dp[c];

  scan_p1_core(c, ch, b, a2, dtb, xact, hbuf, sumdt);
  grid.sync();
  if (gid < BSZ * DINNER * DSTATE)
    scan_comb_core(gid, hbuf, sumdt, A_log);
  grid.sync();
  scan_p3_core(c, ch, b, a2, dp, dtb, xact, xz, hbuf, yg);
}

// standalone fallback kernels
__global__ __launch_bounds__(256, 2)
void scan_pass1(const u16* __restrict__ dtb, const u16* __restrict__ xact,
                const float* __restrict__ A_log,
                u16* __restrict__ hbuf, float* __restrict__ sumdt) {
  const int gid = blockIdx.x * 256 + threadIdx.x;
  const int c  = gid & (DINNER - 1);
  const int ch = (gid >> 11) & (NCH - 1);
  const int b  = gid >> 17;
  float a2[16];
#pragma unroll
  for (int s = 0; s < 16; ++s)
    a2[s] = -__expf(A_log[c * DSTATE + s]) * LOG2E;
  scan_p1_core(c, ch, b, a2, dtb, xact, hbuf, sumdt);
}

__global__ __launch_bounds__(256)
void scan_combine(u16* __restrict__ hbuf, const float* __restrict__ sumdt,
                  const float* __restrict__ A_log) {
  const int gid = blockIdx.x * 256 + threadIdx.x;
  scan_comb_core(gid, hbuf, sumdt, A_log);
}

__global__ __launch_bounds__(256, 2)
void scan_pass3(const u16* __restrict__ dtb, const u16* __restrict__ xact,
                const u16* __restrict__ xz, const float* __restrict__ A_log,
                const float* __restrict__ Dp, const u16* __restrict__ hbuf,
                u16* __restrict__ yg) {
  const int gid = blockIdx.x * 256 + threadIdx.x;
  const int c  = gid & (DINNER - 1);
  const int ch = (gid >> 11) & (NCH - 1);
  const int b  = gid >> 17;
  float a2[16];
#pragma unroll
  for (int s = 0; s < 16; ++s)
    a2[s] = -__expf(A_log[c * DSTATE + s]) * LOG2E;
  scan_p3_core(c, ch, b, a2, Dp[c], dtb, xact, xz, hbuf, yg);
}

extern "C" void kernel_launch(void* const* d_in, const int* in_sizes, int n_in,
                              void* d_out, int out_size, void* d_ws, size_t ws_size,
                              hipStream_t stream) {
  const float* x      = (const float*)d_in[0];
  const float* W_in   = (const float*)d_in[1];
  const float* conv_w = (const float*)d_in[2];
  const float* conv_b = (const float*)d_in[3];
  const float* A_log  = (const float*)d_in[4];
  const float* Dp     = (const float*)d_in[5];
  const float* W_dt   = (const float*)d_in[6];
  const float* b_dt   = (const float*)d_in[7];
  const float* W_out  = (const float*)d_in[8];
  float* out = (float*)d_out;

  // workspace layout (~125 MB)
  u16* xz   = (u16*)d_ws;                                // rm [4096,4096] 32 MB
  u16* dtb  = xz   + (size_t)MTOT * 2 * DINNER;          // rm [4096,2048] 16 MB
  u16* xbf  = dtb  + (size_t)MTOT * DINNER;              // x bf16          8 MB
  u16* wibf = xbf  + (size_t)MTOT * DMODEL;              // W_in bf16       8 MB
  u16* wdbf = wibf + (size_t)2 * DINNER * DMODEL;        // W_dt bf16       8 MB
  u16* wobf = wdbf + (size_t)DINNER * DINNER;            // W_out bf16      4 MB
  u16* xact = wobf + (size_t)DMODEL * DINNER;            // x_act bf16     16 MB
  u16* yg   = xact + (size_t)MTOT * DINNER;              // y_gated bf16   16 MB
  u16* hbuf = yg   + (size_t)MTOT * DINNER;              // [B,NCH,D,16] bf16 8 MB
  float* sumdt = (float*)(hbuf + (size_t)BSZ * NCH * DINNER * 16); // f32 1 MB

  const dim3 blk(256);

  static bool s_attr = false;
  if (!s_attr) {
    hipFuncSetAttribute(reinterpret_cast<const void*>(&gemm8p<256, 0, 1>),
                        hipFuncAttributeMaxDynamicSharedMemorySize, 131072);
    hipFuncSetAttribute(reinterpret_cast<const void*>(&gemm8p<128, 1, 1>),
                        hipFuncAttributeMaxDynamicSharedMemorySize, 98304);
    s_attr = true;
  }

  // 0) all casts in one dispatch
  const int n0 = MTOT * DMODEL / 4, n1 = 2 * DINNER * DMODEL / 4;
  const int n2 = DINNER * DINNER / 4, n3 = DMODEL * DINNER / 4;
  cast4<<<(n0 + n1 + n2 + n3) / 256, blk, 0, stream>>>(
      (const float4*)x, (ushort4*)xbf, n0,
      (const float4*)W_in, (ushort4*)wibf, n1,
      (const float4*)W_dt, (ushort4*)wdbf, n2,
      (const float4*)W_out, (ushort4*)wobf, n3);

  // 1) xz = x @ W_in^T (bf16 out), 256x256 tiles -> 256 blocks = 1/CU
  gemm8p<256, 0, 1><<<(MTOT / 256) * (2 * DINNER / 256), dim3(512), 131072, stream>>>(
      xbf, wibf, nullptr, xz, MTOT, 2 * DINNER, DMODEL);
  // 2) x_act = silu(conv(x_proj) + conv_b), bf16
  conv_silu<<<(MTOT * 256) / 256, blk, 0, stream>>>(xz, conv_w, conv_b, xact);
  // 3) dt = softplus(x_act @ W_dt^T + b_dt), 256x128 tiles -> 256 blocks
  gemm8p<128, 1, 1><<<(MTOT / 256) * (DINNER / 128), dim3(512), 98304, stream>>>(
      xact, wdbf, b_dt, dtb, MTOT, DINNER, DINNER);

  // 4) chunked selective scan + D skip + gate: fused cooperative (1 dispatch),
  //    guarded fallback to the 3-kernel form if coop launch is unavailable.
  {
    const u16* dtb_c = dtb; const u16* xact_c = xact; const u16* xz_c = xz;
    void* kargs[] = { (void*)&dtb_c, (void*)&xact_c, (void*)&xz_c,
                      (void*)&A_log, (void*)&Dp, (void*)&hbuf,
                      (void*)&sumdt, (void*)&yg };
    hipError_t ce = hipLaunchCooperativeKernel(
        reinterpret_cast<const void*>(&scan_fused),
        dim3(BSZ * NCH * DINNER / 256), dim3(256), kargs, 0, stream);
    if (ce != hipSuccess) {
      (void)hipGetLastError();   // clear error state
      scan_pass1<<<BSZ * NCH * DINNER / 256, blk, 0, stream>>>(dtb, xact, A_log, hbuf, sumdt);
      scan_combine<<<BSZ * DINNER * 16 / 256, blk, 0, stream>>>(hbuf, sumdt, A_log);
      scan_pass3<<<BSZ * NCH * DINNER / 256, blk, 0, stream>>>(dtb, xact, xz, A_log, Dp, hbuf, yg);
    }
  }

  // 5) out = y_gated @ W_out^T (fp32 out), 128x64 tiles, BK=128
  hgemm_bk128<0, 0, 64><<<(MTOT / 128) * (DMODEL / 64), blk, 0, stream>>>(
      yg, wobf, nullptr, out, MTOT, DMODEL, DINNER);
}

// Round 7
// 274.275 us; speedup vs baseline: 1.9798x; 1.9798x over previous
//
#include <hip/hip_runtime.h>

#define DMODEL 1024
#define DSTATE 16
#define DCONV  4
#define DINNER 2048
#define BSZ    2
#define LSEQ   2048
#define MTOT   (BSZ * LSEQ)   // 4096 rows for all GEMMs
#define NCH    64             // scan chunks per sequence
#define LC     (LSEQ / NCH)   // 32 timesteps per chunk
#define LOG2E  1.44269504088896f

typedef unsigned short u16;
typedef __attribute__((ext_vector_type(8))) short short8;           // 8 bf16 (MFMA A/B frag)
typedef __attribute__((ext_vector_type(8))) unsigned short u16x8;   // 16B bf16 chunk
typedef __attribute__((ext_vector_type(4))) float f32x4;            // MFMA C/D frag

__device__ __forceinline__ float silu_f(float v) {
  return v * __builtin_amdgcn_rcpf(1.f + __builtin_amdgcn_exp2f(-v * LOG2E));
}

__device__ __forceinline__ u16 f2bf(float f) {   // RNE f32 -> bf16
  unsigned int u = __float_as_uint(f);
  u += 0x7FFF + ((u >> 16) & 1);
  return (u16)(u >> 16);
}
__device__ __forceinline__ float bf2f(u16 b) { return __uint_as_float(((unsigned int)b) << 16); }

// async global->LDS, 16B/lane; LDS dest = wave-uniform base + lane*16 (m104)
__device__ __forceinline__ void gload_lds16(const u16* g, u16* l) {
  __builtin_amdgcn_global_load_lds((const __attribute__((address_space(1))) unsigned int*)g,
                                   (__attribute__((address_space(3))) unsigned int*)l, 16, 0, 0);
}

// All four f32->bf16 casts in one dispatch (x, W_in, W_dt, W_out), row-major
__global__ __launch_bounds__(256)
void cast4(const float4* __restrict__ s0, ushort4* __restrict__ d0, int n0,
           const float4* __restrict__ s1, ushort4* __restrict__ d1, int n1,
           const float4* __restrict__ s2, ushort4* __restrict__ d2, int n2,
           const float4* __restrict__ s3, ushort4* __restrict__ d3, int n3) {
  int i = blockIdx.x * 256 + threadIdx.x;
  const float4* s; ushort4* d;
  if (i < n0)                { s = s0; d = d0; }
  else if ((i -= n0) < n1)   { s = s1; d = d1; }
  else if ((i -= n1) < n2)   { s = s2; d = d2; }
  else if ((i -= n2) < n3)   { s = s3; d = d3; }
  else return;
  float4 v = s[i];
  ushort4 o = { f2bf(v.x), f2bf(v.y), f2bf(v.z), f2bf(v.w) };
  d[i] = o;
}

// ---- single-barrier phased 256xBN GEMM (round-3 best-measured form) --------
// BK=64 per K-tile, 2 K-tiles per iteration, 8 waves (4M x 2N), per-wave
// output 64 x BN/2; 16 MFMA per phase. LDS double-buffer A[2][256][64] +
// B[2][BN][64] (128 KB / 96 KB, dynamic). fm/gsz 4-M-group block swizzle.
// Phase = { ds_reads; STG; MFMA x16; lgkmcnt(0); [vmcnt(4) at K-tile end];
//           s_barrier }. Direct scalar C stores (measured best r3 vs r4).
// MODE 0: plain. MODE 1: softplus(C + bias[col]). MODE 2: silu(C) for tiles
// with bn >= N/2 (block-uniform; fuses the z-gate activation into GEMM1).
template<int BN, int MODE, int OBF>
__global__ __launch_bounds__(512, 2)
void gemm8p(const u16* __restrict__ A, const u16* __restrict__ Bm,
            const float* __restrict__ bias, void* __restrict__ Cv,
            int M, int N, int K) {
  constexpr int BT  = BN / 32;    // B frags per wave (8 or 4)
  constexpr int TJP = 2;          // tj per phase -> 16 MFMA per phase
  constexpr int NPH = BT / TJP;   // phases per K-tile (4 or 2)
  constexpr int NBH = BN / 128;   // B half-tiles per K-tile (2 or 1)
  extern __shared__ __align__(16) u16 smem[];
  u16* As = smem;                     // [2][256][64]
  u16* Bs = smem + 2 * 256 * 64;      // [2][BN][64]

  const int tid  = threadIdx.x;
  const int lane = tid & 63;
  const int w    = tid >> 6;
  const int quad = lane >> 4;
  const int l16  = lane & 15;
  const int wm   = (w >> 1) * 64;         // 4 M-warps
  const int wn   = (w & 1) * (BN / 2);    // 2 N-warps

  const int nbn = N / BN, nbm = M >> 8;
  const int pid = blockIdx.x;
  const int npg = 4 * nbn;
  const int fm  = (pid / npg) * 4;
  const int gsz = (nbm - fm < 4) ? (nbm - fm) : 4;
  const int bm  = (fm + (pid % gsz)) << 8;
  const int bn  = ((pid % npg) / gsz) * BN;

  const int rseg = lane >> 3;
  const int cd8  = (((lane & 7) ^ rseg) << 3);
  const u16* gA = A  + (size_t)(bm + 16 * w + rseg) * K + cd8;
  const u16* gB = Bm + (size_t)(bn + 16 * w + rseg) * K + cd8;
  u16* lA = &As[(2 * w) << 9];
  u16* lB = &Bs[(2 * w) << 9];
  const int Kmask = K - 1;

  auto stA = [&](int slot, int h, int kt) {   // stage A half-tile h of K-tile kt
    const size_t go = (size_t)h * 128 * K + ((kt << 6) & Kmask);
    gload_lds16(gA + go,         lA + slot * 16384 + h * 8192);
    gload_lds16(gA + go + 8 * K, lA + slot * 16384 + h * 8192 + 512);
  };
  auto stB = [&](int slot, int h, int kt) {
    const size_t go = (size_t)h * 128 * K + ((kt << 6) & Kmask);
    gload_lds16(gB + go,         lB + slot * (BN * 64) + h * 8192);
    gload_lds16(gB + go + 8 * K, lB + slot * (BN * 64) + h * 8192 + 512);
  };

  int aoff[4][2], boff[BT][2];
#pragma unroll
  for (int t = 0; t < 4; ++t) {
    const int ra = wm + 16 * t + l16;
#pragma unroll
    for (int ks = 0; ks < 2; ++ks)
      aoff[t][ks] = ra * 64 + (((quad + 4 * ks) ^ (ra & 7)) << 3);
  }
#pragma unroll
  for (int tj = 0; tj < BT; ++tj) {
    const int rb = wn + 16 * tj + l16;
#pragma unroll
    for (int ks = 0; ks < 2; ++ks)
      boff[tj][ks] = rb * 64 + (((quad + 4 * ks) ^ (rb & 7)) << 3);
  }

  f32x4 acc[4][BT] = {};
  short8 af[4][2];

#define RD_AF(slot)                                                          \
  { _Pragma("unroll") for (int t = 0; t < 4; ++t)                            \
      _Pragma("unroll") for (int ks = 0; ks < 2; ++ks)                       \
        af[t][ks] = *(const short8*)&As[(slot) * 16384 + aoff[t][ks]]; }

#define VM4 asm volatile("s_waitcnt vmcnt(4)" ::: "memory")
#define NOWAIT ((void)0)

#define PHASE(slot, j, STG, WAIT)                                            \
  {                                                                          \
    if ((j) == 0) RD_AF(slot);                                               \
    short8 bfp[TJP][2];                                                      \
    _Pragma("unroll") for (int jj = 0; jj < TJP; ++jj)                       \
      _Pragma("unroll") for (int ks = 0; ks < 2; ++ks)                       \
        bfp[jj][ks] = *(const short8*)&Bs[(slot) * (BN * 64) +               \
                                          boff[(j) * TJP + jj][ks]];         \
    STG;                                                                     \
    __builtin_amdgcn_s_setprio(1);                                           \
    _Pragma("unroll") for (int ks = 0; ks < 2; ++ks)                         \
      _Pragma("unroll") for (int jj = 0; jj < TJP; ++jj)                     \
        _Pragma("unroll") for (int t = 0; t < 4; ++t)                        \
          acc[t][(j) * TJP + jj] = __builtin_amdgcn_mfma_f32_16x16x32_bf16(  \
              af[t][ks], bfp[jj][ks], acc[t][(j) * TJP + jj], 0, 0, 0);      \
    __builtin_amdgcn_s_setprio(0);                                           \
    asm volatile("s_waitcnt lgkmcnt(0)" ::: "memory");                       \
    WAIT;                                                                    \
    __builtin_amdgcn_s_barrier();                                            \
  }

  stA(0, 0, 0); stA(0, 1, 0);
  stB(0, 0, 0); if (NBH == 2) stB(0, 1, 0);
  stA(1, 0, 1); stA(1, 1, 1);
  VM4;
  __builtin_amdgcn_s_barrier();

  const int niter = K >> 7;
  for (int i = 0; i < niter; ++i) {
    const int tb1 = 2 * i + 1, t2 = 2 * i + 2, t3 = 2 * i + 3;
    if constexpr (NPH == 4) {
      PHASE(0, 0, { stB(1, 0, tb1); },               NOWAIT);
      PHASE(0, 1, { stB(1, 1, tb1); stA(0, 0, t2); }, NOWAIT);
      PHASE(0, 2, { stA(0, 1, t2); },                NOWAIT);
      PHASE(0, 3, {},                                VM4);
      PHASE(1, 0, { stB(0, 0, t2); },                NOWAIT);
      PHASE(1, 1, { stB(0, 1, t2); stA(1, 0, t3); }, NOWAIT);
      PHASE(1, 2, { stA(1, 1, t3); },                NOWAIT);
      PHASE(1, 3, {},                                VM4);
    } else {
      PHASE(0, 0, { stB(1, 0, tb1); },                NOWAIT);
      PHASE(0, 1, { stA(0, 0, t2); stA(0, 1, t2); },  VM4);
      PHASE(1, 0, { stB(0, 0, t2); },                 NOWAIT);
      PHASE(1, 1, { stA(1, 0, t3); stA(1, 1, t3); },  VM4);
    }
  }
#undef PHASE
#undef RD_AF
#undef VM4
#undef NOWAIT

  asm volatile("s_waitcnt vmcnt(0)" ::: "memory");   // drain wrapped prefetches

  // C/D: col = lane&15, row = quad*4 + reg (m89/m91)
  const bool dosilu = (MODE == 2) && (bn >= (N >> 1));   // block-uniform
#pragma unroll
  for (int t = 0; t < 4; ++t) {
    const int row0 = bm + wm + 16 * t + quad * 4;
#pragma unroll
    for (int tj = 0; tj < BT; ++tj) {
      const int col = bn + wn + 16 * tj + l16;
      const float bv = (MODE == 1) ? bias[col] : 0.f;
#pragma unroll
      for (int i2 = 0; i2 < 4; ++i2) {
        float v = acc[t][tj][i2] + bv;
        if (MODE == 1) v = (v > 20.f) ? v : __logf(1.f + __expf(v));   // softplus
        if (MODE == 2 && dosilu) v = silu_f(v);                        // z-gate
        if (OBF) ((u16*)Cv)[(size_t)(row0 + i2) * N + col] = f2bf(v);
        else     ((float*)Cv)[(size_t)(row0 + i2) * N + col] = v;
      }
    }
  }
}

// ---- 128xBN-tile GEMM, BK=128 (GEMM3 BN=64; round-0 measured form) ---------
template<int MODE, int OBF, int BN>
__global__ __launch_bounds__(256)
void hgemm_bk128(const u16* __restrict__ A, const u16* __restrict__ B,
                 const float* __restrict__ bias, void* __restrict__ Cv,
                 int M, int N, int K) {
  constexpr int ASEG = 32;            // A: 128 rows x 256 B = 32 KB
  constexpr int BSEG = BN / 4;        // B: BN rows x 256 B
  constexpr int SPW  = (ASEG + BSEG) / 4;
  constexpr int BT   = BN / 32;       // B frags per wave (4 or 2)
  __shared__ u16 As[128 * 128];       // 32 KB
  __shared__ u16 Bs[BN * 128];        // 32 or 16 KB
  const int tid  = threadIdx.x;
  const int lane = tid & 63;
  const int w    = tid >> 6;
  const int quad = lane >> 4;
  const int l16  = lane & 15;

  const int nbn = N / BN, nbm = M >> 7;
  const int pid = blockIdx.x;
  const int npg = 4 * nbn;
  const int fm  = (pid / npg) * 4;
  const int gsz = (nbm - fm < 4) ? (nbm - fm) : 4;
  const int bm  = (fm + (pid % gsz)) << 7;
  const int bn  = ((pid % npg) / gsz) * BN;

  const int wm = (w & 1) * 64;
  const int wn = (w >> 1) * (BN / 2);

  const int rs4 = lane >> 4;
  const u16* Gp[SPW]; u16* Lp[SPW];
#pragma unroll
  for (int q = 0; q < SPW; ++q) {
    const int g = w * SPW + q;
    if (g < ASEG) {
      const int r  = g * 4 + rs4;
      const int cdk = (lane & 15) ^ (r & 15);
      Gp[q] = A + (size_t)(bm + r) * K + (cdk << 3);
      Lp[q] = &As[g << 9];
    } else {
      const int r  = (g - ASEG) * 4 + rs4;
      const int cdk = (lane & 15) ^ (r & 15);
      Gp[q] = B + (size_t)(bn + r) * K + (cdk << 3);
      Lp[q] = &Bs[(g - ASEG) << 9];
    }
  }

  const short8* Afp[4][4];
  const short8* Bfp[BT][4];
#pragma unroll
  for (int t = 0; t < 4; ++t) {
    const int ra = wm + 16 * t + l16;
#pragma unroll
    for (int ks = 0; ks < 4; ++ks)
      Afp[t][ks] = (const short8*)&As[ra * 128 + (((quad + 4 * ks) ^ (ra & 15)) << 3)];
  }
#pragma unroll
  for (int t = 0; t < BT; ++t) {
    const int rb = wn + 16 * t + l16;
#pragma unroll
    for (int ks = 0; ks < 4; ++ks)
      Bfp[t][ks] = (const short8*)&Bs[rb * 128 + (((quad + 4 * ks) ^ (rb & 15)) << 3)];
  }

  f32x4 acc[4][BT] = {};

  for (int k0 = 0; k0 < K; k0 += 128) {
#pragma unroll
    for (int q = 0; q < SPW; ++q) { gload_lds16(Gp[q], Lp[q]); Gp[q] += 128; }
    __syncthreads();
#pragma unroll
    for (int ks = 0; ks < 4; ++ks) {
      short8 af[4], bf[BT];
#pragma unroll
      for (int t = 0; t < 4; ++t) af[t] = *Afp[t][ks];
#pragma unroll
      for (int t = 0; t < BT; ++t) bf[t] = *Bfp[t][ks];
#pragma unroll
      for (int ti = 0; ti < 4; ++ti)
#pragma unroll
        for (int tj = 0; tj < BT; ++tj)
          acc[ti][tj] = __builtin_amdgcn_mfma_f32_16x16x32_bf16(af[ti], bf[tj],
                                                                acc[ti][tj], 0, 0, 0);
    }
    __syncthreads();
  }

#pragma unroll
  for (int ti = 0; ti < 4; ++ti) {
    const int row0 = bm + wm + 16 * ti + quad * 4;
#pragma unroll
    for (int tj = 0; tj < BT; ++tj) {
      const int col = bn + wn + 16 * tj + l16;
      const float bv = (MODE == 1) ? bias[col] : 0.f;
#pragma unroll
      for (int i = 0; i < 4; ++i) {
        float v = acc[ti][tj][i] + bv;
        if (MODE == 1) v = (v > 20.f) ? v : __logf(1.f + __expf(v));
        if (OBF) ((u16*)Cv)[(size_t)(row0 + i) * N + col] = f2bf(v);
        else     ((float*)Cv)[(size_t)(row0 + i) * N + col] = v;
      }
    }
  }
}

// depthwise causal conv1d (taps=4) + bias + SiLU.
// Thread computes 4 consecutive timesteps for one 8-channel octet via a
// 7-row register window: 1.75 row-loads/output instead of 4 (r7 change).
__global__ __launch_bounds__(256)
void conv_silu(const u16* __restrict__ xz, const float* __restrict__ conv_w,
               const float* __restrict__ conv_b, u16* __restrict__ xact) {
  const int i  = blockIdx.x * 256 + threadIdx.x;  // 2^18: b(1) t4(9) ko(8)
  const int ko = i & 255;
  const int t4 = (i >> 8) & (LSEQ / 4 - 1);
  const int b  = i >> 17;
  const int c  = ko << 3;
  const int t0 = t4 << 2;
  float wv[4][8], bias[8];
#pragma unroll
  for (int j = 0; j < 8; ++j) {
    bias[j] = conv_b[c + j];
    const float4 w4 = *(const float4*)(conv_w + (c + j) * DCONV);
    wv[0][j] = w4.x; wv[1][j] = w4.y; wv[2][j] = w4.z; wv[3][j] = w4.w;
  }
  float win[7][8];
#pragma unroll
  for (int r = 0; r < 7; ++r) {
    const int tt = t0 - 3 + r;
    if (tt >= 0) {
      const u16x8 v = *(const u16x8*)(xz + ((size_t)(b * LSEQ + tt) << 12) + c);
#pragma unroll
      for (int j = 0; j < 8; ++j) win[r][j] = bf2f(v[j]);
    } else {
#pragma unroll
      for (int j = 0; j < 8; ++j) win[r][j] = 0.f;
    }
  }
#pragma unroll
  for (int o = 0; o < 4; ++o) {   // output row t0+o uses win[o..o+3]
    u16x8 outv;
#pragma unroll
    for (int j = 0; j < 8; ++j) {
      float a = bias[j];
#pragma unroll
      for (int k = 0; k < 4; ++k) a = fmaf(win[o + k][j], wv[k][j], a);
      outv[j] = f2bf(silu_f(a));
    }
    *(u16x8*)(xact + ((size_t)(b * LSEQ + t0 + o) << 11) + c) = outv;
  }
}

// ---- chunked parallel scan (3-kernel form; hbuf in bf16) -------------------

__global__ __launch_bounds__(256, 2)
void scan_pass1(const u16* __restrict__ dtb, const u16* __restrict__ xact,
                const float* __restrict__ A_log,
                u16* __restrict__ hbuf, float* __restrict__ sumdt) {
  const int gid = blockIdx.x * 256 + threadIdx.x;  // 2^18 lanes, c fastest
  const int c  = gid & (DINNER - 1);
  const int ch = (gid >> 11) & (NCH - 1);
  const int b  = gid >> 17;
  float a2[16];
#pragma unroll
  for (int s = 0; s < 16; ++s)
    a2[s] = -__expf(A_log[c * DSTATE + s]) * LOG2E;   // exp(dt*a) = exp2(dt*a2)
  const size_t base = ((size_t)(b * LSEQ + ch * LC) << 11) + c;
  float h[16] = {};
  float sd = 0.f;
  for (int j = 0; j < LC; j += 2) {
    const float dt0 = bf2f(dtb [base + ((size_t)j << 11)]);
    const float xv0 = bf2f(xact[base + ((size_t)j << 11)]);
    const float dt1 = bf2f(dtb [base + ((size_t)(j + 1) << 11)]);
    const float xv1 = bf2f(xact[base + ((size_t)(j + 1) << 11)]);
    const float dx0 = dt0 * xv0, dx1 = dt1 * xv1;
    sd += dt0 + dt1;
#pragma unroll
    for (int s = 0; s < 16; ++s)
      h[s] = fmaf(__builtin_amdgcn_exp2f(dt0 * a2[s]), h[s], dx0);
#pragma unroll
    for (int s = 0; s < 16; ++s)
      h[s] = fmaf(__builtin_amdgcn_exp2f(dt1 * a2[s]), h[s], dx1);
  }
  u16x8* ho = (u16x8*)&hbuf[(((size_t)(b * NCH + ch) * DINNER) + c) << 4];
  u16x8 lo, hi;
#pragma unroll
  for (int s = 0; s < 8; ++s) { lo[s] = f2bf(h[s]); hi[s] = f2bf(h[8 + s]); }
  ho[0] = lo; ho[1] = hi;
  sumdt[(size_t)(b * NCH + ch) * DINNER + c] = sd;
}

__global__ __launch_bounds__(256)
void scan_combine(u16* __restrict__ hbuf, const float* __restrict__ sumdt,
                  const float* __restrict__ A_log) {
  const int gid = blockIdx.x * 256 + threadIdx.x;  // 2^16: b*32768 + c*16 + s
  const int s = gid & 15;
  const int c = (gid >> 4) & (DINNER - 1);
  const int b = gid >> 15;
  const float a2 = -__expf(A_log[c * DSTATE + s]) * LOG2E;
  float h = 0.f;
  for (int k = 0; k < NCH; ++k) {
    const size_t o = (((size_t)(b * NCH + k) * DINNER) + c) * 16 + s;
    const float he = bf2f(hbuf[o]);
    const float sd = sumdt[(size_t)(b * NCH + k) * DINNER + c];
    hbuf[o] = f2bf(h);                    // h_start for chunk k
    h = fmaf(__builtin_amdgcn_exp2f(sd * a2), h, he);
  }
}

// Pass 3: re-scan from h_start; y = sum_s h + Dp*x; gate with PRE-SILU'd z
// (GEMM1 MODE=2 already applied silu to the z half of xz); bf16 rm out.
__global__ __launch_bounds__(256, 2)
void scan_pass3(const u16* __restrict__ dtb, const u16* __restrict__ xact,
                const u16* __restrict__ xz, const float* __restrict__ A_log,
                const float* __restrict__ Dp, const u16* __restrict__ hbuf,
                u16* __restrict__ yg) {
  const int gid = blockIdx.x * 256 + threadIdx.x;
  const int c  = gid & (DINNER - 1);
  const int ch = (gid >> 11) & (NCH - 1);
  const int b  = gid >> 17;
  float a2[16];
#pragma unroll
  for (int s = 0; s < 16; ++s)
    a2[s] = -__expf(A_log[c * DSTATE + s]) * LOG2E;
  const float dp = Dp[c];
  float h[16];
  const u16x8* hi = (const u16x8*)&hbuf[(((size_t)(b * NCH + ch) * DINNER) + c) << 4];
  const u16x8 vlo = hi[0], vhi = hi[1];
#pragma unroll
  for (int s = 0; s < 8; ++s) { h[s] = bf2f(vlo[s]); h[8 + s] = bf2f(vhi[s]); }
  const size_t base  = ((size_t)(b * LSEQ + ch * LC) << 11) + c;
  const size_t zbase = ((size_t)(b * LSEQ + ch * LC) << 12) + DINNER + c;
  for (int j = 0; j < LC; j += 2) {
    const float dt0 = bf2f(dtb [base + ((size_t)j << 11)]);
    const float xv0 = bf2f(xact[base + ((size_t)j << 11)]);
    const float zv0 = bf2f(xz[zbase + ((size_t)j << 12)]);      // = silu(z)
    const float dt1 = bf2f(dtb [base + ((size_t)(j + 1) << 11)]);
    const float xv1 = bf2f(xact[base + ((size_t)(j + 1) << 11)]);
    const float zv1 = bf2f(xz[zbase + ((size_t)(j + 1) << 12)]);
    const float dx0 = dt0 * xv0, dx1 = dt1 * xv1;
    float y0 = 0.f, y1 = 0.f;
#pragma unroll
    for (int s = 0; s < 16; ++s) {
      h[s] = fmaf(__builtin_amdgcn_exp2f(dt0 * a2[s]), h[s], dx0);
      y0 += h[s];
    }
#pragma unroll
    for (int s = 0; s < 16; ++s) {
      h[s] = fmaf(__builtin_amdgcn_exp2f(dt1 * a2[s]), h[s], dx1);
      y1 += h[s];
    }
    y0 = fmaf(dp, xv0, y0);
    y1 = fmaf(dp, xv1, y1);
    yg[base + ((size_t)j << 11)]       = f2bf(y0 * zv0);
    yg[base + ((size_t)(j + 1) << 11)] = f2bf(y1 * zv1);
  }
}

extern "C" void kernel_launch(void* const* d_in, const int* in_sizes, int n_in,
                              void* d_out, int out_size, void* d_ws, size_t ws_size,
                              hipStream_t stream) {
  const float* x      = (const float*)d_in[0];
  const float* W_in   = (const float*)d_in[1];
  const float* conv_w = (const float*)d_in[2];
  const float* conv_b = (const float*)d_in[3];
  const float* A_log  = (const float*)d_in[4];
  const float* Dp     = (const float*)d_in[5];
  const float* W_dt   = (const float*)d_in[6];
  const float* b_dt   = (const float*)d_in[7];
  const float* W_out  = (const float*)d_in[8];
  float* out = (float*)d_out;

  // workspace layout (~125 MB)
  u16* xz   = (u16*)d_ws;                                // rm [4096,4096] 32 MB
  u16* dtb  = xz   + (size_t)MTOT * 2 * DINNER;          // rm [4096,2048] 16 MB
  u16* xbf  = dtb  + (size_t)MTOT * DINNER;              // x bf16          8 MB
  u16* wibf = xbf  + (size_t)MTOT * DMODEL;              // W_in bf16       8 MB
  u16* wdbf = wibf + (size_t)2 * DINNER * DMODEL;        // W_dt bf16       8 MB
  u16* wobf = wdbf + (size_t)DINNER * DINNER;            // W_out bf16      4 MB
  u16* xact = wobf + (size_t)DMODEL * DINNER;            // x_act bf16     16 MB
  u16* yg   = xact + (size_t)MTOT * DINNER;              // y_gated bf16   16 MB
  u16* hbuf = yg   + (size_t)MTOT * DINNER;              // [B,NCH,D,16] bf16 8 MB
  float* sumdt = (float*)(hbuf + (size_t)BSZ * NCH * DINNER * 16); // f32 1 MB

  const dim3 blk(256);

  static bool s_attr = false;
  if (!s_attr) {
    hipFuncSetAttribute(reinterpret_cast<const void*>(&gemm8p<256, 2, 1>),
                        hipFuncAttributeMaxDynamicSharedMemorySize, 131072);
    hipFuncSetAttribute(reinterpret_cast<const void*>(&gemm8p<128, 1, 1>),
                        hipFuncAttributeMaxDynamicSharedMemorySize, 98304);
    s_attr = true;
  }

  // 0) all casts in one dispatch
  const int n0 = MTOT * DMODEL / 4, n1 = 2 * DINNER * DMODEL / 4;
  const int n2 = DINNER * DINNER / 4, n3 = DMODEL * DINNER / 4;
  cast4<<<(n0 + n1 + n2 + n3) / 256, blk, 0, stream>>>(
      (const float4*)x, (ushort4*)xbf, n0,
      (const float4*)W_in, (ushort4*)wibf, n1,
      (const float4*)W_dt, (ushort4*)wdbf, n2,
      (const float4*)W_out, (ushort4*)wobf, n3);

  // 1) xz = x @ W_in^T (bf16 out; z half pre-silu'd), 256x256 tiles
  gemm8p<256, 2, 1><<<(MTOT / 256) * (2 * DINNER / 256), dim3(512), 131072, stream>>>(
      xbf, wibf, nullptr, xz, MTOT, 2 * DINNER, DMODEL);
  // 2) x_act = silu(conv(x_proj) + conv_b), bf16; 4 timesteps/thread
  conv_silu<<<(BSZ * (LSEQ / 4) * 256) / 256, blk, 0, stream>>>(xz, conv_w, conv_b, xact);
  // 3) dt = softplus(x_act @ W_dt^T + b_dt), 256x128 tiles
  gemm8p<128, 1, 1><<<(MTOT / 256) * (DINNER / 128), dim3(512), 98304, stream>>>(
      xact, wdbf, b_dt, dtb, MTOT, DINNER, DINNER);
  // 4) chunked selective scan + D skip + gate (hbuf bf16)
  scan_pass1<<<BSZ * NCH * DINNER / 256, blk, 0, stream>>>(dtb, xact, A_log, hbuf, sumdt);
  scan_combine<<<BSZ * DINNER * 16 / 256, blk, 0, stream>>>(hbuf, sumdt, A_log);
  scan_pass3<<<BSZ * NCH * DINNER / 256, blk, 0, stream>>>(dtb, xact, xz, A_log, Dp, hbuf, yg);
  // 5) out = y_gated @ W_out^T (fp32 out), 128x64 tiles, BK=128
  hgemm_bk128<0, 0, 64><<<(MTOT / 128) * (DMODEL / 64), blk, 0, stream>>>(
      yg, wobf, nullptr, out, MTOT, DMODEL, DINNER);
}

// Round 8
// 273.731 us; speedup vs baseline: 1.9838x; 1.0020x over previous
//
#include <hip/hip_runtime.h>

#define DMODEL 1024
#define DSTATE 16
#define DCONV  4
#define DINNER 2048
#define BSZ    2
#define LSEQ   2048
#define MTOT   (BSZ * LSEQ)   // 4096 rows for all GEMMs
#define NCH    64             // scan chunks per sequence
#define LC     (LSEQ / NCH)   // 32 timesteps per chunk
#define LOG2E  1.44269504088896f

typedef unsigned short u16;
typedef __attribute__((ext_vector_type(8))) short short8;           // 8 bf16 (MFMA A/B frag)
typedef __attribute__((ext_vector_type(8))) unsigned short u16x8;   // 16B bf16 chunk
typedef __attribute__((ext_vector_type(4))) float f32x4;            // MFMA C/D frag

__device__ __forceinline__ float silu_f(float v) {
  return v * __builtin_amdgcn_rcpf(1.f + __builtin_amdgcn_exp2f(-v * LOG2E));
}

__device__ __forceinline__ u16 f2bf(float f) {   // RNE f32 -> bf16
  unsigned int u = __float_as_uint(f);
  u += 0x7FFF + ((u >> 16) & 1);
  return (u16)(u >> 16);
}
__device__ __forceinline__ float bf2f(u16 b) { return __uint_as_float(((unsigned int)b) << 16); }

// async global->LDS, 16B/lane; LDS dest = wave-uniform base + lane*16 (m104)
__device__ __forceinline__ void gload_lds16(const u16* g, u16* l) {
  __builtin_amdgcn_global_load_lds((const __attribute__((address_space(1))) unsigned int*)g,
                                   (__attribute__((address_space(3))) unsigned int*)l, 16, 0, 0);
}

// All four f32->bf16 casts in one dispatch (x, W_in, W_dt, W_out), row-major
__global__ __launch_bounds__(256)
void cast4(const float4* __restrict__ s0, ushort4* __restrict__ d0, int n0,
           const float4* __restrict__ s1, ushort4* __restrict__ d1, int n1,
           const float4* __restrict__ s2, ushort4* __restrict__ d2, int n2,
           const float4* __restrict__ s3, ushort4* __restrict__ d3, int n3) {
  int i = blockIdx.x * 256 + threadIdx.x;
  const float4* s; ushort4* d;
  if (i < n0)                { s = s0; d = d0; }
  else if ((i -= n0) < n1)   { s = s1; d = d1; }
  else if ((i -= n1) < n2)   { s = s2; d = d2; }
  else if ((i -= n2) < n3)   { s = s3; d = d3; }
  else return;
  float4 v = s[i];
  ushort4 o = { f2bf(v.x), f2bf(v.y), f2bf(v.z), f2bf(v.w) };
  d[i] = o;
}

// ---- single-barrier phased 256xBN GEMM (round-3 best-measured form) --------
// BK=64 per K-tile, 2 K-tiles per iteration, 8 waves (4M x 2N), per-wave
// output 64 x BN/2; 16 MFMA per phase. LDS double-buffer A[2][256][64] +
// B[2][BN][64] (128 KB / 96 KB, dynamic). fm/gsz 4-M-group block swizzle.
// Phase = { ds_reads; STG; MFMA x16; lgkmcnt(0); [vmcnt(4) at K-tile end];
//           s_barrier }. Direct scalar C stores (measured best r3 vs r4).
// MODE 0: plain. MODE 1: softplus(C + bias[col]). MODE 2: silu(C) for tiles
// with bn >= N/2 (block-uniform; fuses the z-gate activation into GEMM1).
template<int BN, int MODE, int OBF>
__global__ __launch_bounds__(512, 2)
void gemm8p(const u16* __restrict__ A, const u16* __restrict__ Bm,
            const float* __restrict__ bias, void* __restrict__ Cv,
            int M, int N, int K) {
  constexpr int BT  = BN / 32;    // B frags per wave (8 or 4)
  constexpr int TJP = 2;          // tj per phase -> 16 MFMA per phase
  constexpr int NPH = BT / TJP;   // phases per K-tile (4 or 2)
  constexpr int NBH = BN / 128;   // B half-tiles per K-tile (2 or 1)
  extern __shared__ __align__(16) u16 smem[];
  u16* As = smem;                     // [2][256][64]
  u16* Bs = smem + 2 * 256 * 64;      // [2][BN][64]

  const int tid  = threadIdx.x;
  const int lane = tid & 63;
  const int w    = tid >> 6;
  const int quad = lane >> 4;
  const int l16  = lane & 15;
  const int wm   = (w >> 1) * 64;         // 4 M-warps
  const int wn   = (w & 1) * (BN / 2);    // 2 N-warps

  const int nbn = N / BN, nbm = M >> 8;
  const int pid = blockIdx.x;
  const int npg = 4 * nbn;
  const int fm  = (pid / npg) * 4;
  const int gsz = (nbm - fm < 4) ? (nbm - fm) : 4;
  const int bm  = (fm + (pid % gsz)) << 8;
  const int bn  = ((pid % npg) / gsz) * BN;

  const int rseg = lane >> 3;
  const int cd8  = (((lane & 7) ^ rseg) << 3);
  const u16* gA = A  + (size_t)(bm + 16 * w + rseg) * K + cd8;
  const u16* gB = Bm + (size_t)(bn + 16 * w + rseg) * K + cd8;
  u16* lA = &As[(2 * w) << 9];
  u16* lB = &Bs[(2 * w) << 9];
  const int Kmask = K - 1;

  auto stA = [&](int slot, int h, int kt) {   // stage A half-tile h of K-tile kt
    const size_t go = (size_t)h * 128 * K + ((kt << 6) & Kmask);
    gload_lds16(gA + go,         lA + slot * 16384 + h * 8192);
    gload_lds16(gA + go + 8 * K, lA + slot * 16384 + h * 8192 + 512);
  };
  auto stB = [&](int slot, int h, int kt) {
    const size_t go = (size_t)h * 128 * K + ((kt << 6) & Kmask);
    gload_lds16(gB + go,         lB + slot * (BN * 64) + h * 8192);
    gload_lds16(gB + go + 8 * K, lB + slot * (BN * 64) + h * 8192 + 512);
  };

  int aoff[4][2], boff[BT][2];
#pragma unroll
  for (int t = 0; t < 4; ++t) {
    const int ra = wm + 16 * t + l16;
#pragma unroll
    for (int ks = 0; ks < 2; ++ks)
      aoff[t][ks] = ra * 64 + (((quad + 4 * ks) ^ (ra & 7)) << 3);
  }
#pragma unroll
  for (int tj = 0; tj < BT; ++tj) {
    const int rb = wn + 16 * tj + l16;
#pragma unroll
    for (int ks = 0; ks < 2; ++ks)
      boff[tj][ks] = rb * 64 + (((quad + 4 * ks) ^ (rb & 7)) << 3);
  }

  f32x4 acc[4][BT] = {};
  short8 af[4][2];

#define RD_AF(slot)                                                          \
  { _Pragma("unroll") for (int t = 0; t < 4; ++t)                            \
      _Pragma("unroll") for (int ks = 0; ks < 2; ++ks)                       \
        af[t][ks] = *(const short8*)&As[(slot) * 16384 + aoff[t][ks]]; }

#define VM4 asm volatile("s_waitcnt vmcnt(4)" ::: "memory")
#define NOWAIT ((void)0)

#define PHASE(slot, j, STG, WAIT)                                            \
  {                                                                          \
    if ((j) == 0) RD_AF(slot);                                               \
    short8 bfp[TJP][2];                                                      \
    _Pragma("unroll") for (int jj = 0; jj < TJP; ++jj)                       \
      _Pragma("unroll") for (int ks = 0; ks < 2; ++ks)                       \
        bfp[jj][ks] = *(const short8*)&Bs[(slot) * (BN * 64) +               \
                                          boff[(j) * TJP + jj][ks]];         \
    STG;                                                                     \
    __builtin_amdgcn_s_setprio(1);                                           \
    _Pragma("unroll") for (int ks = 0; ks < 2; ++ks)                         \
      _Pragma("unroll") for (int jj = 0; jj < TJP; ++jj)                     \
        _Pragma("unroll") for (int t = 0; t < 4; ++t)                        \
          acc[t][(j) * TJP + jj] = __builtin_amdgcn_mfma_f32_16x16x32_bf16(  \
              af[t][ks], bfp[jj][ks], acc[t][(j) * TJP + jj], 0, 0, 0);      \
    __builtin_amdgcn_s_setprio(0);                                           \
    asm volatile("s_waitcnt lgkmcnt(0)" ::: "memory");                       \
    WAIT;                                                                    \
    __builtin_amdgcn_s_barrier();                                            \
  }

  stA(0, 0, 0); stA(0, 1, 0);
  stB(0, 0, 0); if (NBH == 2) stB(0, 1, 0);
  stA(1, 0, 1); stA(1, 1, 1);
  VM4;
  __builtin_amdgcn_s_barrier();

  const int niter = K >> 7;
  for (int i = 0; i < niter; ++i) {
    const int tb1 = 2 * i + 1, t2 = 2 * i + 2, t3 = 2 * i + 3;
    if constexpr (NPH == 4) {
      PHASE(0, 0, { stB(1, 0, tb1); },               NOWAIT);
      PHASE(0, 1, { stB(1, 1, tb1); stA(0, 0, t2); }, NOWAIT);
      PHASE(0, 2, { stA(0, 1, t2); },                NOWAIT);
      PHASE(0, 3, {},                                VM4);
      PHASE(1, 0, { stB(0, 0, t2); },                NOWAIT);
      PHASE(1, 1, { stB(0, 1, t2); stA(1, 0, t3); }, NOWAIT);
      PHASE(1, 2, { stA(1, 1, t3); },                NOWAIT);
      PHASE(1, 3, {},                                VM4);
    } else {
      PHASE(0, 0, { stB(1, 0, tb1); },                NOWAIT);
      PHASE(0, 1, { stA(0, 0, t2); stA(0, 1, t2); },  VM4);
      PHASE(1, 0, { stB(0, 0, t2); },                 NOWAIT);
      PHASE(1, 1, { stA(1, 0, t3); stA(1, 1, t3); },  VM4);
    }
  }
#undef PHASE
#undef RD_AF
#undef VM4
#undef NOWAIT

  asm volatile("s_waitcnt vmcnt(0)" ::: "memory");   // drain wrapped prefetches

  // C/D: col = lane&15, row = quad*4 + reg (m89/m91)
  const bool dosilu = (MODE == 2) && (bn >= (N >> 1));   // block-uniform
#pragma unroll
  for (int t = 0; t < 4; ++t) {
    const int row0 = bm + wm + 16 * t + quad * 4;
#pragma unroll
    for (int tj = 0; tj < BT; ++tj) {
      const int col = bn + wn + 16 * tj + l16;
      const float bv = (MODE == 1) ? bias[col] : 0.f;
#pragma unroll
      for (int i2 = 0; i2 < 4; ++i2) {
        float v = acc[t][tj][i2] + bv;
        if (MODE == 1) v = (v > 20.f) ? v : __logf(1.f + __expf(v));   // softplus
        if (MODE == 2 && dosilu) v = silu_f(v);                        // z-gate
        if (OBF) ((u16*)Cv)[(size_t)(row0 + i2) * N + col] = f2bf(v);
        else     ((float*)Cv)[(size_t)(row0 + i2) * N + col] = v;
      }
    }
  }
}

// ---- 128xBN-tile GEMM, BK=128 (GEMM3; BN=128 this round) -------------------
// 2-phase structure: stage full K-tile, sync, 4 ks-steps x 16 MFMA = 64 MFMA
// per barrier window (good amortization even at 1 block/CU).
template<int MODE, int OBF, int BN>
__global__ __launch_bounds__(256)
void hgemm_bk128(const u16* __restrict__ A, const u16* __restrict__ B,
                 const float* __restrict__ bias, void* __restrict__ Cv,
                 int M, int N, int K) {
  constexpr int ASEG = 32;            // A: 128 rows x 256 B = 32 KB
  constexpr int BSEG = BN / 4;        // B: BN rows x 256 B
  constexpr int SPW  = (ASEG + BSEG) / 4;
  constexpr int BT   = BN / 32;       // B frags per wave (4 or 2)
  __shared__ u16 As[128 * 128];       // 32 KB
  __shared__ u16 Bs[BN * 128];        // 32 or 16 KB
  const int tid  = threadIdx.x;
  const int lane = tid & 63;
  const int w    = tid >> 6;
  const int quad = lane >> 4;
  const int l16  = lane & 15;

  const int nbn = N / BN, nbm = M >> 7;
  const int pid = blockIdx.x;
  const int npg = 4 * nbn;
  const int fm  = (pid / npg) * 4;
  const int gsz = (nbm - fm < 4) ? (nbm - fm) : 4;
  const int bm  = (fm + (pid % gsz)) << 7;
  const int bn  = ((pid % npg) / gsz) * BN;

  const int wm = (w & 1) * 64;
  const int wn = (w >> 1) * (BN / 2);

  const int rs4 = lane >> 4;
  const u16* Gp[SPW]; u16* Lp[SPW];
#pragma unroll
  for (int q = 0; q < SPW; ++q) {
    const int g = w * SPW + q;
    if (g < ASEG) {
      const int r  = g * 4 + rs4;
      const int cdk = (lane & 15) ^ (r & 15);
      Gp[q] = A + (size_t)(bm + r) * K + (cdk << 3);
      Lp[q] = &As[g << 9];
    } else {
      const int r  = (g - ASEG) * 4 + rs4;
      const int cdk = (lane & 15) ^ (r & 15);
      Gp[q] = B + (size_t)(bn + r) * K + (cdk << 3);
      Lp[q] = &Bs[(g - ASEG) << 9];
    }
  }

  const short8* Afp[4][4];
  const short8* Bfp[BT][4];
#pragma unroll
  for (int t = 0; t < 4; ++t) {
    const int ra = wm + 16 * t + l16;
#pragma unroll
    for (int ks = 0; ks < 4; ++ks)
      Afp[t][ks] = (const short8*)&As[ra * 128 + (((quad + 4 * ks) ^ (ra & 15)) << 3)];
  }
#pragma unroll
  for (int t = 0; t < BT; ++t) {
    const int rb = wn + 16 * t + l16;
#pragma unroll
    for (int ks = 0; ks < 4; ++ks)
      Bfp[t][ks] = (const short8*)&Bs[rb * 128 + (((quad + 4 * ks) ^ (rb & 15)) << 3)];
  }

  f32x4 acc[4][BT] = {};

  for (int k0 = 0; k0 < K; k0 += 128) {
#pragma unroll
    for (int q = 0; q < SPW; ++q) { gload_lds16(Gp[q], Lp[q]); Gp[q] += 128; }
    __syncthreads();
#pragma unroll
    for (int ks = 0; ks < 4; ++ks) {
      short8 af[4], bf[BT];
#pragma unroll
      for (int t = 0; t < 4; ++t) af[t] = *Afp[t][ks];
#pragma unroll
      for (int t = 0; t < BT; ++t) bf[t] = *Bfp[t][ks];
#pragma unroll
      for (int ti = 0; ti < 4; ++ti)
#pragma unroll
        for (int tj = 0; tj < BT; ++tj)
          acc[ti][tj] = __builtin_amdgcn_mfma_f32_16x16x32_bf16(af[ti], bf[tj],
                                                                acc[ti][tj], 0, 0, 0);
    }
    __syncthreads();
  }

#pragma unroll
  for (int ti = 0; ti < 4; ++ti) {
    const int row0 = bm + wm + 16 * ti + quad * 4;
#pragma unroll
    for (int tj = 0; tj < BT; ++tj) {
      const int col = bn + wn + 16 * tj + l16;
      const float bv = (MODE == 1) ? bias[col] : 0.f;
#pragma unroll
      for (int i = 0; i < 4; ++i) {
        float v = acc[ti][tj][i] + bv;
        if (MODE == 1) v = (v > 20.f) ? v : __logf(1.f + __expf(v));
        if (OBF) ((u16*)Cv)[(size_t)(row0 + i) * N + col] = f2bf(v);
        else     ((float*)Cv)[(size_t)(row0 + i) * N + col] = v;
      }
    }
  }
}

// depthwise causal conv1d (taps=4) + bias + SiLU.
// Thread computes 4 consecutive timesteps for one 8-channel octet via a
// 7-row register window: 1.75 row-loads/output instead of 4.
__global__ __launch_bounds__(256)
void conv_silu(const u16* __restrict__ xz, const float* __restrict__ conv_w,
               const float* __restrict__ conv_b, u16* __restrict__ xact) {
  const int i  = blockIdx.x * 256 + threadIdx.x;  // 2^18: b(1) t4(9) ko(8)
  const int ko = i & 255;
  const int t4 = (i >> 8) & (LSEQ / 4 - 1);
  const int b  = i >> 17;
  const int c  = ko << 3;
  const int t0 = t4 << 2;
  float wv[4][8], bias[8];
#pragma unroll
  for (int j = 0; j < 8; ++j) {
    bias[j] = conv_b[c + j];
    const float4 w4 = *(const float4*)(conv_w + (c + j) * DCONV);
    wv[0][j] = w4.x; wv[1][j] = w4.y; wv[2][j] = w4.z; wv[3][j] = w4.w;
  }
  float win[7][8];
#pragma unroll
  for (int r = 0; r < 7; ++r) {
    const int tt = t0 - 3 + r;
    if (tt >= 0) {
      const u16x8 v = *(const u16x8*)(xz + ((size_t)(b * LSEQ + tt) << 12) + c);
#pragma unroll
      for (int j = 0; j < 8; ++j) win[r][j] = bf2f(v[j]);
    } else {
#pragma unroll
      for (int j = 0; j < 8; ++j) win[r][j] = 0.f;
    }
  }
#pragma unroll
  for (int o = 0; o < 4; ++o) {   // output row t0+o uses win[o..o+3]
    u16x8 outv;
#pragma unroll
    for (int j = 0; j < 8; ++j) {
      float a = bias[j];
#pragma unroll
      for (int k = 0; k < 4; ++k) a = fmaf(win[o + k][j], wv[k][j], a);
      outv[j] = f2bf(silu_f(a));
    }
    *(u16x8*)(xact + ((size_t)(b * LSEQ + t0 + o) << 11) + c) = outv;
  }
}

// ---- chunked parallel scan (3-kernel form; hbuf in bf16) -------------------

__global__ __launch_bounds__(256, 2)
void scan_pass1(const u16* __restrict__ dtb, const u16* __restrict__ xact,
                const float* __restrict__ A_log,
                u16* __restrict__ hbuf, float* __restrict__ sumdt) {
  const int gid = blockIdx.x * 256 + threadIdx.x;  // 2^18 lanes, c fastest
  const int c  = gid & (DINNER - 1);
  const int ch = (gid >> 11) & (NCH - 1);
  const int b  = gid >> 17;
  float a2[16];
#pragma unroll
  for (int s = 0; s < 16; ++s)
    a2[s] = -__expf(A_log[c * DSTATE + s]) * LOG2E;   // exp(dt*a) = exp2(dt*a2)
  const size_t base = ((size_t)(b * LSEQ + ch * LC) << 11) + c;
  float h[16] = {};
  float sd = 0.f;
  for (int j = 0; j < LC; j += 2) {
    const float dt0 = bf2f(dtb [base + ((size_t)j << 11)]);
    const float xv0 = bf2f(xact[base + ((size_t)j << 11)]);
    const float dt1 = bf2f(dtb [base + ((size_t)(j + 1) << 11)]);
    const float xv1 = bf2f(xact[base + ((size_t)(j + 1) << 11)]);
    const float dx0 = dt0 * xv0, dx1 = dt1 * xv1;
    sd += dt0 + dt1;
#pragma unroll
    for (int s = 0; s < 16; ++s)
      h[s] = fmaf(__builtin_amdgcn_exp2f(dt0 * a2[s]), h[s], dx0);
#pragma unroll
    for (int s = 0; s < 16; ++s)
      h[s] = fmaf(__builtin_amdgcn_exp2f(dt1 * a2[s]), h[s], dx1);
  }
  u16x8* ho = (u16x8*)&hbuf[(((size_t)(b * NCH + ch) * DINNER) + c) << 4];
  u16x8 lo, hi;
#pragma unroll
  for (int s = 0; s < 8; ++s) { lo[s] = f2bf(h[s]); hi[s] = f2bf(h[8 + s]); }
  ho[0] = lo; ho[1] = hi;
  sumdt[(size_t)(b * NCH + ch) * DINNER + c] = sd;
}

__global__ __launch_bounds__(256)
void scan_combine(u16* __restrict__ hbuf, const float* __restrict__ sumdt,
                  const float* __restrict__ A_log) {
  const int gid = blockIdx.x * 256 + threadIdx.x;  // 2^16: b*32768 + c*16 + s
  const int s = gid & 15;
  const int c = (gid >> 4) & (DINNER - 1);
  const int b = gid >> 15;
  const float a2 = -__expf(A_log[c * DSTATE + s]) * LOG2E;
  float h = 0.f;
  for (int k = 0; k < NCH; ++k) {
    const size_t o = (((size_t)(b * NCH + k) * DINNER) + c) * 16 + s;
    const float he = bf2f(hbuf[o]);
    const float sd = sumdt[(size_t)(b * NCH + k) * DINNER + c];
    hbuf[o] = f2bf(h);                    // h_start for chunk k
    h = fmaf(__builtin_amdgcn_exp2f(sd * a2), h, he);
  }
}

// Pass 3: re-scan from h_start; y = sum_s h + Dp*x; gate with PRE-SILU'd z
// (GEMM1 MODE=2 already applied silu to the z half of xz); bf16 rm out.
__global__ __launch_bounds__(256, 2)
void scan_pass3(const u16* __restrict__ dtb, const u16* __restrict__ xact,
                const u16* __restrict__ xz, const float* __restrict__ A_log,
                const float* __restrict__ Dp, const u16* __restrict__ hbuf,
                u16* __restrict__ yg) {
  const int gid = blockIdx.x * 256 + threadIdx.x;
  const int c  = gid & (DINNER - 1);
  const int ch = (gid >> 11) & (NCH - 1);
  const int b  = gid >> 17;
  float a2[16];
#pragma unroll
  for (int s = 0; s < 16; ++s)
    a2[s] = -__expf(A_log[c * DSTATE + s]) * LOG2E;
  const float dp = Dp[c];
  float h[16];
  const u16x8* hi = (const u16x8*)&hbuf[(((size_t)(b * NCH + ch) * DINNER) + c) << 4];
  const u16x8 vlo = hi[0], vhi = hi[1];
#pragma unroll
  for (int s = 0; s < 8; ++s) { h[s] = bf2f(vlo[s]); h[8 + s] = bf2f(vhi[s]); }
  const size_t base  = ((size_t)(b * LSEQ + ch * LC) << 11) + c;
  const size_t zbase = ((size_t)(b * LSEQ + ch * LC) << 12) + DINNER + c;
  for (int j = 0; j < LC; j += 2) {
    const float dt0 = bf2f(dtb [base + ((size_t)j << 11)]);
    const float xv0 = bf2f(xact[base + ((size_t)j << 11)]);
    const float zv0 = bf2f(xz[zbase + ((size_t)j << 12)]);      // = silu(z)
    const float dt1 = bf2f(dtb [base + ((size_t)(j + 1) << 11)]);
    const float xv1 = bf2f(xact[base + ((size_t)(j + 1) << 11)]);
    const float zv1 = bf2f(xz[zbase + ((size_t)(j + 1) << 12)]);
    const float dx0 = dt0 * xv0, dx1 = dt1 * xv1;
    float y0 = 0.f, y1 = 0.f;
#pragma unroll
    for (int s = 0; s < 16; ++s) {
      h[s] = fmaf(__builtin_amdgcn_exp2f(dt0 * a2[s]), h[s], dx0);
      y0 += h[s];
    }
#pragma unroll
    for (int s = 0; s < 16; ++s) {
      h[s] = fmaf(__builtin_amdgcn_exp2f(dt1 * a2[s]), h[s], dx1);
      y1 += h[s];
    }
    y0 = fmaf(dp, xv0, y0);
    y1 = fmaf(dp, xv1, y1);
    yg[base + ((size_t)j << 11)]       = f2bf(y0 * zv0);
    yg[base + ((size_t)(j + 1) << 11)] = f2bf(y1 * zv1);
  }
}

extern "C" void kernel_launch(void* const* d_in, const int* in_sizes, int n_in,
                              void* d_out, int out_size, void* d_ws, size_t ws_size,
                              hipStream_t stream) {
  const float* x      = (const float*)d_in[0];
  const float* W_in   = (const float*)d_in[1];
  const float* conv_w = (const float*)d_in[2];
  const float* conv_b = (const float*)d_in[3];
  const float* A_log  = (const float*)d_in[4];
  const float* Dp     = (const float*)d_in[5];
  const float* W_dt   = (const float*)d_in[6];
  const float* b_dt   = (const float*)d_in[7];
  const float* W_out  = (const float*)d_in[8];
  float* out = (float*)d_out;

  // workspace layout (~125 MB)
  u16* xz   = (u16*)d_ws;                                // rm [4096,4096] 32 MB
  u16* dtb  = xz   + (size_t)MTOT * 2 * DINNER;          // rm [4096,2048] 16 MB
  u16* xbf  = dtb  + (size_t)MTOT * DINNER;              // x bf16          8 MB
  u16* wibf = xbf  + (size_t)MTOT * DMODEL;              // W_in bf16       8 MB
  u16* wdbf = wibf + (size_t)2 * DINNER * DMODEL;        // W_dt bf16       8 MB
  u16* wobf = wdbf + (size_t)DINNER * DINNER;            // W_out bf16      4 MB
  u16* xact = wobf + (size_t)DMODEL * DINNER;            // x_act bf16     16 MB
  u16* yg   = xact + (size_t)MTOT * DINNER;              // y_gated bf16   16 MB
  u16* hbuf = yg   + (size_t)MTOT * DINNER;              // [B,NCH,D,16] bf16 8 MB
  float* sumdt = (float*)(hbuf + (size_t)BSZ * NCH * DINNER * 16); // f32 1 MB

  const dim3 blk(256);

  static bool s_attr = false;
  if (!s_attr) {
    hipFuncSetAttribute(reinterpret_cast<const void*>(&gemm8p<256, 2, 1>),
                        hipFuncAttributeMaxDynamicSharedMemorySize, 131072);
    hipFuncSetAttribute(reinterpret_cast<const void*>(&gemm8p<128, 1, 1>),
                        hipFuncAttributeMaxDynamicSharedMemorySize, 98304);
    s_attr = true;
  }

  // 0) all casts in one dispatch
  const int n0 = MTOT * DMODEL / 4, n1 = 2 * DINNER * DMODEL / 4;
  const int n2 = DINNER * DINNER / 4, n3 = DMODEL * DINNER / 4;
  cast4<<<(n0 + n1 + n2 + n3) / 256, blk, 0, stream>>>(
      (const float4*)x, (ushort4*)xbf, n0,
      (const float4*)W_in, (ushort4*)wibf, n1,
      (const float4*)W_dt, (ushort4*)wdbf, n2,
      (const float4*)W_out, (ushort4*)wobf, n3);

  // 1) xz = x @ W_in^T (bf16 out; z half pre-silu'd), 256x256 tiles
  gemm8p<256, 2, 1><<<(MTOT / 256) * (2 * DINNER / 256), dim3(512), 131072, stream>>>(
      xbf, wibf, nullptr, xz, MTOT, 2 * DINNER, DMODEL);
  // 2) x_act = silu(conv(x_proj) + conv_b), bf16; 4 timesteps/thread
  conv_silu<<<(BSZ * (LSEQ / 4) * 256) / 256, blk, 0, stream>>>(xz, conv_w, conv_b, xact);
  // 3) dt = softplus(x_act @ W_dt^T + b_dt), 256x128 tiles
  gemm8p<128, 1, 1><<<(MTOT / 256) * (DINNER / 128), dim3(512), 98304, stream>>>(
      xact, wdbf, b_dt, dtb, MTOT, DINNER, DINNER);
  // 4) chunked selective scan + D skip + gate (hbuf bf16)
  scan_pass1<<<BSZ * NCH * DINNER / 256, blk, 0, stream>>>(dtb, xact, A_log, hbuf, sumdt);
  scan_combine<<<BSZ * DINNER * 16 / 256, blk, 0, stream>>>(hbuf, sumdt, A_log);
  scan_pass3<<<BSZ * NCH * DINNER / 256, blk, 0, stream>>>(dtb, xact, xz, A_log, Dp, hbuf, yg);
  // 5) out = y_gated @ W_out^T (fp32 out), 128x128 tiles (BT=4, 64 MFMA/window)
  hgemm_bk128<0, 0, 128><<<(MTOT / 128) * (DMODEL / 128), blk, 0, stream>>>(
      yg, wobf, nullptr, out, MTOT, DMODEL, DINNER);
}